// Round 1
// baseline (732.450 us; speedup 1.0000x reference)
//
#include <hip/hip_runtime.h>
#include <stdint.h>

#define DIN   64
#define HDIM  64
#define EIN   16
#define EHID  128     // edge hidden width
#define HH    4096    // HDIM*HDIM
#define TC    8256    // BmatT rows: 8192 main + 64 bias
#define STEPS 3

typedef short bf16x8 __attribute__((ext_vector_type(8)));
typedef float f32x4  __attribute__((ext_vector_type(4)));

__device__ __forceinline__ unsigned short f32_to_bf16(float f) {
    union { float f; uint32_t u; } v; v.f = f;
    uint32_t r = v.u + 0x7fffu + ((v.u >> 16) & 1u);   // RNE
    return (unsigned short)(r >> 16);
}
__device__ __forceinline__ float bfu_to_f(unsigned short u) {
    union { uint32_t u; float f; } v; v.u = (uint32_t)u << 16; return v.f;
}

// ---- merged prologue: [0,nbN) node_mlp | [nbN,+nbE) edge_mlp(MFMA) | [+nbB) bmat | rest hist ----
__global__ void k_pro(const float* __restrict__ nf, const float* __restrict__ W0,
                      const float* __restrict__ b0, float* __restrict__ outb,
                      unsigned short* __restrict__ outbf,
                      const float* __restrict__ ef, const float* __restrict__ We1,
                      const float* __restrict__ be1, unsigned short* __restrict__ h,
                      const float* __restrict__ We2, const float* __restrict__ be2,
                      unsigned short* __restrict__ BmatT,
                      const int* __restrict__ src, const int* __restrict__ dst,
                      int* __restrict__ cntS, int* __restrict__ cntD,
                      int n_nodes, int n_edges, int nbN, int nbE, int nbB) {
    __shared__ float smem[DIN * HDIM];   // 16 KB (node path only)
    int b = blockIdx.x, tid = threadIdx.x;
    if (b < nbN) {
        // node MLP: out[n,o] = relu(n_feat[n,:]@W0[:,o]+b0[o]); 4 nodes/block
        for (int i = tid; i < DIN * HDIM; i += 256) smem[i] = W0[i];
        __syncthreads();
        int node = b * 4 + (tid >> 6);
        int o = tid & 63;
        if (node >= n_nodes) return;
        float xr = nf[node * DIN + o];
        float acc = b0[o];
#pragma unroll 8
        for (int i = 0; i < DIN; ++i)
            acc += __shfl(xr, i, 64) * smem[i * HDIM + o];
        float v = fmaxf(acc, 0.f);
        outb[node * HDIM + o] = v;
        outbf[node * HDIM + o] = f32_to_bf16(v);
    } else if (b < nbN + nbE) {
        // edge MLP via MFMA: 64 edges/block (16/wave), K=16 zero-padded to 32.
        // h stored with per-64-group col perm sigma (inverse baked into BmatT k-index).
        int wave = tid >> 6, lane = tid & 63;
        int r = lane & 15, q = lane >> 4;
        int e0 = (b - nbN) * 64 + wave * 16;
        if (e0 >= n_edges) return;           // wave-uniform
        bf16x8 afr = (bf16x8){};
        bf16x8 bfr[8];
#pragma unroll
        for (int nt = 0; nt < 8; ++nt) bfr[nt] = (bf16x8){};
        if (q < 2) {
            int ea = e0 + r; if (ea >= n_edges) ea = n_edges - 1;
            const float* xa = ef + (size_t)ea * EIN + q * 8;
#pragma unroll
            for (int j = 0; j < 8; ++j) afr[j] = (short)f32_to_bf16(xa[j]);
#pragma unroll
            for (int nt = 0; nt < 8; ++nt)
#pragma unroll
                for (int j = 0; j < 8; ++j)
                    bfr[nt][j] = (short)f32_to_bf16(We1[(q * 8 + j) * EHID + nt * 16 + r]);
        }
        f32x4 acc[8];
#pragma unroll
        for (int nt = 0; nt < 8; ++nt)
            acc[nt] = __builtin_amdgcn_mfma_f32_16x16x32_bf16(afr, bfr[nt], (f32x4){}, 0, 0, 0);
        float bias[8];
#pragma unroll
        for (int nt = 0; nt < 8; ++nt) bias[nt] = be1[nt * 16 + r];
#pragma unroll
        for (int rg = 0; rg < 4; ++rg) {
            int e = e0 + q * 4 + rg;         // C/D: col=lane&15, row=quad*4+reg
            if (e >= n_edges) continue;
            ushort4 pk0, pk1;
            pk0.x = f32_to_bf16(fmaxf(acc[0][rg] + bias[0], 0.f));
            pk0.y = f32_to_bf16(fmaxf(acc[1][rg] + bias[1], 0.f));
            pk0.z = f32_to_bf16(fmaxf(acc[2][rg] + bias[2], 0.f));
            pk0.w = f32_to_bf16(fmaxf(acc[3][rg] + bias[3], 0.f));
            pk1.x = f32_to_bf16(fmaxf(acc[4][rg] + bias[4], 0.f));
            pk1.y = f32_to_bf16(fmaxf(acc[5][rg] + bias[5], 0.f));
            pk1.z = f32_to_bf16(fmaxf(acc[6][rg] + bias[6], 0.f));
            pk1.w = f32_to_bf16(fmaxf(acc[7][rg] + bias[7], 0.f));
            *(ushort4*)(h + (size_t)e * EHID + 4 * r) = pk0;
            *(ushort4*)(h + (size_t)e * EHID + 64 + 4 * r) = pk1;
        }
    } else if (b < nbN + nbE + nbB) {
        // BmatT for the fused kernel. Row m (< 8192):
        //   oc = m>>11 (o-chunk), o_in = (m&2047)>>7, nt = (m>>4)&7, r1 = m&15
        //   K  = r1*8 + nt   (h PHYSICAL column this row pairs with in phase-2)
        //   true channel k = h's stored->true map at p=K
        //   o_true = oc*16 + o_in  (msg stored PLAIN)
        // Rows 8192..8255: bias, o_true = m-8192.
        int t = (b - nbN - nbE) * 256 + tid;
        if (t >= TC * 64) return;
        int m = t >> 6, i = t & 63;
        float v;
        if (m < 8192) {
            int oc = m >> 11, c2 = m & 2047;
            int o  = oc * 16 + (c2 >> 7);
            int K  = ((c2 & 15) << 3) | ((c2 >> 4) & 7);
            int k  = (K & 64) + ((K & 3) << 4) + ((K >> 2) & 15);
            v = We2[k * HH + i * 64 + o];
        } else {
            v = be2[i * 64 + (m - 8192)];
        }
        BmatT[m * 64 + i] = f32_to_bf16(v);
    } else {
        // histogram src and dst
        int e = (b - nbN - nbE - nbB) * 256 + tid;
        if (e >= n_edges) return;
        atomicAdd(&cntS[src[e]], 1);
        atomicAdd(&cntD[dst[e]], 1);
    }
}

// Fused T+msg: block = 16 src nodes. For each of 4 o-chunks:
//   phase1: T[16n][128K][16o] chunk -> LDS (one full 16-row M-tile, B streamed from L2)
//   phase2: msg[:, oc*16..+16) for all edges of these nodes (offS/permS grouping)
// LDS layout per node: [o(16) rows][128 K], 16B slot index XOR-swizzled with (o&7)
// so both ds_write_b128 (phase1) and ds_read_b128 (phase2) hit the 8-cycle floor.
__global__ void k_fused(const unsigned short* __restrict__ outbf,
                        const unsigned short* __restrict__ BmatT,
                        const unsigned short* __restrict__ h,
                        const int* __restrict__ offS, const int* __restrict__ permS,
                        float* __restrict__ msg, int n_nodes) {
    __shared__ short Tlds[16 * 2048];   // 64 KB, one o-chunk for 16 nodes
    __shared__ float Tb[16 * 64];       // 4 KB bias (all 64 cols)
    int wave = threadIdx.x >> 6, lane = threadIdx.x & 63;
    int r = lane & 15, q = lane >> 4;
    int n0 = blockIdx.x * 16;

    // A fragments: x rows for the 16 nodes (A row r = node n0+r), reused all chunks
    int na = n0 + r; if (na >= n_nodes) na = n_nodes - 1;
    bf16x8 afr0 = *(const bf16x8*)(outbf + (size_t)na * 64 + q * 8);
    bf16x8 afr1 = *(const bf16x8*)(outbf + (size_t)na * 64 + 32 + q * 8);

    // bias tile: wave ob covers o = ob*16 + r
    {
        size_t cofs = (size_t)(8192 + wave * 16 + r) * 64;
        bf16x8 bb0 = *(const bf16x8*)(BmatT + cofs + q * 8);
        bf16x8 bb1 = *(const bf16x8*)(BmatT + cofs + 32 + q * 8);
        f32x4 accB = __builtin_amdgcn_mfma_f32_16x16x32_bf16(afr0, bb0, (f32x4){}, 0, 0, 0);
        accB = __builtin_amdgcn_mfma_f32_16x16x32_bf16(afr1, bb1, accB, 0, 0, 0);
#pragma unroll
        for (int rg = 0; rg < 4; ++rg)
            Tb[(q * 4 + rg) * 64 + wave * 16 + r] = accB[rg];
    }

    int nlim = n_nodes - n0; if (nlim > 16) nlim = 16;

    for (int oc = 0; oc < 4; ++oc) {
        __syncthreads();   // prev-chunk phase2 done; (first iter: Tb ready)
        // ---- phase 1: compute T chunk oc into LDS ----
#pragma unroll
        for (int og = 0; og < 4; ++og) {
            int o_in = wave * 4 + og;
            f32x4 a8[8];
#pragma unroll
            for (int nt = 0; nt < 8; ++nt) {
                size_t cofs = (size_t)(oc * 2048 + (o_in * 8 + nt) * 16 + r) * 64;
                bf16x8 bv0 = *(const bf16x8*)(BmatT + cofs + q * 8);
                bf16x8 bv1 = *(const bf16x8*)(BmatT + cofs + 32 + q * 8);
                a8[nt] = __builtin_amdgcn_mfma_f32_16x16x32_bf16(afr0, bv0, (f32x4){}, 0, 0, 0);
                a8[nt] = __builtin_amdgcn_mfma_f32_16x16x32_bf16(afr1, bv1, a8[nt], 0, 0, 0);
            }
            // lane holds (node = q*4+rg, col r1 = r, K = r*8 + nt); pack nt -> 16B write
#pragma unroll
            for (int rg = 0; rg < 4; ++rg) {
                bf16x8 pk;
#pragma unroll
                for (int nt = 0; nt < 8; ++nt)
                    pk[nt] = (short)f32_to_bf16(a8[nt][rg]);
                *(bf16x8*)((char*)Tlds + ((q * 4 + rg) << 12) + (o_in << 8)
                           + (((r ^ (o_in & 7)) & 15) << 4)) = pk;
            }
        }
        __syncthreads();
        // ---- phase 2: msg columns [oc*16, oc*16+16) for this block's edges ----
        int tt = 0;
        for (int ni = 0; ni < nlim; ++ni) {
            int beg = offS[n0 + ni], end = offS[n0 + ni + 1];
            for (int j0 = beg; j0 < end; j0 += 16, ++tt) {
                if ((tt & 3) != wave) continue;       // wave-uniform
                int jc = j0 + r; if (jc >= end) jc = end - 1;
                int e = permS[jc];
                const unsigned short* he = h + (size_t)e * EHID;
                f32x4 acc = {};
#pragma unroll
                for (int ks = 0; ks < 4; ++ks) {
                    bf16x8 afr = *(const bf16x8*)(he + ks * 32 + q * 8);
                    bf16x8 bfr = *(const bf16x8*)((char*)Tlds + (ni << 12) + (r << 8)
                                   + ((((ks * 4 + q) ^ (r & 7)) & 15) << 4));
                    acc = __builtin_amdgcn_mfma_f32_16x16x32_bf16(afr, bfr, acc, 0, 0, 0);
                }
                float bias = Tb[ni * 64 + oc * 16 + r];
#pragma unroll
                for (int rg = 0; rg < 4; ++rg) {      // C/D: col=lane&15, row=q*4+rg
                    int jr = j0 + q * 4 + rg;
                    if (jr >= end) continue;
                    int er = permS[jr];
                    msg[(size_t)er * 64 + oc * 16 + r] = acc[rg] + bias;
                }
            }
        }
    }
}

// exclusive prefix sum (one block per array; blockIdx.x: 0=S, 1=D)
__global__ void k_scan(const int* __restrict__ cntS, const int* __restrict__ cntD,
                       int* __restrict__ offS, int* __restrict__ offD,
                       int* __restrict__ curS, int* __restrict__ curD, int n, int total) {
    const int* cnt = blockIdx.x ? cntD : cntS;
    int* off = blockIdx.x ? offD : offS;
    int* cur = blockIdx.x ? curD : curS;
    __shared__ int part[256];
    int tid = threadIdx.x;
    int chunk = (n + 255) / 256;
    int c0 = tid * chunk, c1 = c0 + chunk; if (c1 > n) c1 = n; if (c0 > n) c0 = n;
    int s = 0;
    for (int i = c0; i < c1; ++i) s += cnt[i];
    part[tid] = s;
    __syncthreads();
    for (int st = 1; st < 256; st <<= 1) {
        int v = (tid >= st) ? part[tid - st] : 0;
        __syncthreads();
        part[tid] += v;
        __syncthreads();
    }
    int run = tid ? part[tid - 1] : 0;
    for (int i = c0; i < c1; ++i) { off[i] = run; cur[i] = run; run += cnt[i]; }
    if (tid == 0) off[n] = total;
}

__global__ void k_perm(const int* __restrict__ src, const int* __restrict__ dst,
                       int* __restrict__ curS, int* __restrict__ curD,
                       int* __restrict__ permS, int* __restrict__ permD, int n_edges) {
    int e = blockIdx.x * 256 + threadIdx.x;
    if (e >= n_edges) return;
    permS[atomicAdd(&curS[src[e]], 1)] = e;
    permD[atomicAdd(&curD[dst[e]], 1)] = e;
}

// per dst-node wave: out[d] = relu(sum msg + cbias); atomic-free. msg is PLAIN now.
__global__ void k_agg(const float* __restrict__ msg, const int* __restrict__ offD,
                      const int* __restrict__ permD, const float* __restrict__ cbias,
                      float* __restrict__ outb, unsigned short* __restrict__ outbf, int n_nodes) {
    int wave = threadIdx.x >> 6, lane = threadIdx.x & 63;
    int d = blockIdx.x * 4 + wave;
    if (d >= n_nodes) return;
    float acc = 0.f;
    int end = offD[d + 1];
    for (int j = offD[d]; j < end; ++j)
        acc += msg[(size_t)permD[j] * 64 + lane];
    float v = fmaxf(acc + cbias[lane], 0.f);
    outb[(size_t)d * 64 + lane] = v;
    outbf[(size_t)d * 64 + lane] = f32_to_bf16(v);
}

// grid MUST be 64 blocks (row stride 256 hardcoded)
__global__ void k_bn_stats(const float* __restrict__ out, float* __restrict__ stat, int n_nodes) {
    __shared__ float s1[256], s2[256];
    int tid = threadIdx.x;
    int f = tid & 63, g = tid >> 6;
    float sum = 0.f, ss = 0.f;
    for (int r = blockIdx.x * 4 + g; r < n_nodes; r += 256) {
        float v = out[r * HDIM + f];
        sum += v; ss += v * v;
    }
    s1[tid] = sum; s2[tid] = ss;
    __syncthreads();
    if (tid < 64) {
        float A = s1[tid] + s1[64 + tid] + s1[128 + tid] + s1[192 + tid];
        float B = s2[tid] + s2[64 + tid] + s2[128 + tid] + s2[192 + tid];
        atomicAdd(&stat[tid], A);
        atomicAdd(&stat[64 + tid], B);
    }
}

// bn_final fused in: every thread derives scale/shift from stat (identical arith)
__global__ void k_bn_apply(const float* __restrict__ out, const float* __restrict__ stat,
                           const float* __restrict__ gamma, const float* __restrict__ beta,
                           float* __restrict__ y, int n, int n_nodes) {
    int t = blockIdx.x * 256 + threadIdx.x;
    if (t >= n) return;
    int f = t & 63;
    float mean = stat[f] / n_nodes;
    float var  = stat[64 + f] / n_nodes - mean * mean;   // population var
    float inv  = rsqrtf(var + 1e-5f);
    float scale = gamma[f] * inv;
    float shift = beta[f] - mean * scale;
    y[t] = out[t] * scale + shift;
}

extern "C" void kernel_launch(void* const* d_in, const int* in_sizes, int n_in,
                              void* d_out, int out_size, void* d_ws, size_t ws_size,
                              hipStream_t stream) {
    const float* nf    = (const float*)d_in[0];
    const float* ef    = (const float*)d_in[1];
    const int*   src   = (const int*)d_in[2];
    const int*   dst   = (const int*)d_in[3];
    const float* W0    = (const float*)d_in[4];
    const float* b0    = (const float*)d_in[5];
    const float* We1   = (const float*)d_in[6];
    const float* be1   = (const float*)d_in[7];
    const float* We2   = (const float*)d_in[8];
    const float* be2   = (const float*)d_in[9];
    const float* cbias = (const float*)d_in[10];
    const float* gamma = (const float*)d_in[11];
    const float* beta  = (const float*)d_in[12];
    (void)n_in; (void)out_size; (void)ws_size;

    int n_nodes = in_sizes[0] / DIN;   // 10000
    int n_edges = in_sizes[2];         // 100000

    char* ws = (char*)d_ws;
    size_t off = 0;
    auto carve = [&](size_t bytes) -> void* {
        void* p = ws + off;
        off = (off + bytes + 255) & ~(size_t)255;
        return p;
    };
    unsigned short* h     = (unsigned short*)carve((size_t)n_edges * EHID * 2);  // 25.6 MB
    float*          msg   = (float*)carve((size_t)n_edges * 64 * 4);             // 25.6 MB
    float*          outb  = (float*)carve((size_t)n_nodes * HDIM * 4);
    unsigned short* outbf = (unsigned short*)carve((size_t)n_nodes * HDIM * 2);
    unsigned short* BmatT = (unsigned short*)carve((size_t)TC * 64 * 2);
    int*            offS  = (int*)carve((size_t)(n_nodes + 1) * 4);
    int*            offD  = (int*)carve((size_t)(n_nodes + 1) * 4);
    int*            curS  = (int*)carve((size_t)n_nodes * 4);
    int*            curD  = (int*)carve((size_t)n_nodes * 4);
    int*            permS = (int*)carve((size_t)n_edges * 4);
    int*            permD = (int*)carve((size_t)n_edges * 4);
    float*          stat  = (float*)carve(128 * 4 + (size_t)2 * n_nodes * 4); // stat + cntS + cntD
    int*            cntS  = (int*)(stat + 128);
    int*            cntD  = cntS + n_nodes;

    hipMemsetAsync(stat, 0, 128 * 4 + (size_t)2 * n_nodes * 4, stream);

    int nbN = (n_nodes + 3) / 4;            // 2500
    int nbE = (n_edges + 63) / 64;          // 1563 (MFMA edge path: 64 edges/block)
    int nbB = (TC * 64 + 255) / 256;        // 2064
    int nbH = (n_edges + 255) / 256;        // 391
    k_pro<<<dim3(nbN + nbE + nbB + nbH), 256, 0, stream>>>(
        nf, W0, b0, outb, outbf, ef, We1, be1, h, We2, be2, BmatT,
        src, dst, cntS, cntD, n_nodes, n_edges, nbN, nbE, nbB);
    k_scan<<<dim3(2), 256, 0, stream>>>(cntS, cntD, offS, offD, curS, curD, n_nodes, n_edges);
    k_perm<<<dim3((n_edges + 255) / 256), 256, 0, stream>>>(src, dst, curS, curD, permS, permD, n_edges);

    int nbF = (n_nodes + 15) / 16;          // 625 fused blocks
    for (int step = 0; step < STEPS; ++step) {
        k_fused<<<dim3(nbF), 256, 0, stream>>>(outbf, BmatT, h, offS, permS, msg, n_nodes);
        k_agg<<<dim3((n_nodes + 3) / 4), 256, 0, stream>>>(msg, offD, permD, cbias, outb, outbf, n_nodes);
    }

    k_bn_stats<<<dim3(64), 256, 0, stream>>>(outb, stat, n_nodes);
    k_bn_apply<<<dim3((n_nodes * HDIM + 255) / 256), 256, 0, stream>>>(
        outb, stat, gamma, beta, (float*)d_out, n_nodes * HDIM, n_nodes);
}